// Round 9
// baseline (167.535 us; speedup 1.0000x reference)
//
#include <hip/hip_runtime.h>

// SelfAttention: B=4, S=2048, D=1024, fp32 in/out. bf16 MFMA, fp32 accum.
// R8: 128x128 / 4-wave / 64KiB-LDS geometry -> 2 blocks/CU (was 1). All grids
// exact multiples of 512 blocks. Schedule = R7 core2 (merged 2-phase, counted
// vmcnt(4), setprio) unchanged -- only geometry/index plumbing differs.
//   proj: grid (64,24) = 1536 = 3 exact rounds (M=8192, N=3072=Wq|Wk|Wv)
//   sc:   grid (16,16,4) = 1024 = 2 rounds, P~=exp(QK^T/32)+rowsum partials
//   pv:   grid (16,8,4)  = 512 = 1 round, * 1/rowsum (in-kernel rsum)
// ws layout (MiB):
//   [0,16)   x_bf16 (proj) -> P~ bf16 [4][2048][2048]
//   [16,32)  Q bf16   [32,48) K bf16   [48,64) Vt bf16 [4][1024][2048]
//   [64,70)  Wq|Wk|Wv bf16
//   [70,+512K) rowpart fp32 [16][4][2048]

typedef __bf16 bf16x8 __attribute__((ext_vector_type(8)));
typedef float f32x4 __attribute__((ext_vector_type(4)));
typedef unsigned short u16;

__device__ __forceinline__ u16 f2b(float f) {
  union { float f; unsigned u; } a; a.f = f;
  unsigned r = a.u + 0x7fffu + ((a.u >> 16) & 1u);  // RNE
  return (u16)(r >> 16);
}

// blocks [0,8192): x (2097152 float4s). blocks [8192,11264): Wq|Wk|Wv.
__global__ __launch_bounds__(256) void cast_all_kernel(const float* __restrict__ x,
                                                       const float* __restrict__ Wq,
                                                       const float* __restrict__ Wk,
                                                       const float* __restrict__ Wv,
                                                       u16* __restrict__ xb,
                                                       u16* __restrict__ Wb) {
  int b = blockIdx.x;
  if (b < 8192) {
    const int i = b * 256 + threadIdx.x;
    float4 v = reinterpret_cast<const float4*>(x)[i];
    reinterpret_cast<ushort4*>(xb)[i] =
        make_ushort4(f2b(v.x), f2b(v.y), f2b(v.z), f2b(v.w));
  } else {
    b -= 8192;
    const int w = b >> 10;
    const float* src = (w == 0) ? Wq : (w == 1) ? Wk : Wv;
    const int i = (b & 1023) * 256 + threadIdx.x;
    float4 v = reinterpret_cast<const float4*>(src)[i];
    reinterpret_cast<ushort4*>(Wb + (size_t)w * 1048576)[i] =
        make_ushort4(f2b(v.x), f2b(v.y), f2b(v.z), f2b(v.w));
  }
}

// ---------------- 128x128 4-wave merged-phase core (R8) ----------------
// 256 threads = 4 waves (wr=wave>>1, wc=wave&1), wave tile 64x64, BK=64,
// NT K-tiles, lda/ldb in BYTES. LDS: 2 bufs x (A 16K + B 16K) = 64 KiB.
// Phase (kt,s): {ds_read 4A+4B frags of K-half s; STAGE half s of kt+1;
// barrier; MFMA 16; counted vmcnt; barrier}. Steady vmcnt(4) (one 4-load
// stage group in flight); tail kt=NT-1: s0 -> vmcnt(0), s1 -> none.
template <int NT>
__device__ __forceinline__ void core128(const char* __restrict__ Ab,
                                        const char* __restrict__ Bb, int lda, int ldb,
                                        char* smem, f32x4* acc) {
  const int tid = threadIdx.x;
  const int wave = tid >> 6, lane = tid & 63;
  const int wr = wave >> 1, wc = wave & 1;
  const int fr = lane & 15, fg = lane >> 4;
  const int rd = (fr * 64 + fg * 16) ^ (((fr >> 3) & 1) << 5);
  const int li = (lane * 16) ^ ((lane >> 5) << 5);
  const int sr = li >> 6, sc2 = li & 63;

  auto STAGE = [&](int kt, int s) {  // A-half s + B-half s of tile kt (4 loads)
    char* base = smem + (kt & 1) * 32768;
    const int colOff = kt * 128 + s * 64 + sc2;
    char* ldsA = base + s * 8192;
    __builtin_amdgcn_global_load_lds(
        (const __attribute__((address_space(1))) void*)(Ab + (size_t)(wave * 16 + sr) * lda + colOff),
        (__attribute__((address_space(3))) void*)(ldsA + wave * 1024), 16, 0, 0);
    __builtin_amdgcn_global_load_lds(
        (const __attribute__((address_space(1))) void*)(Ab + (size_t)(64 + wave * 16 + sr) * lda + colOff),
        (__attribute__((address_space(3))) void*)(ldsA + 4096 + wave * 1024), 16, 0, 0);
    char* ldsB = base + 16384 + s * 8192;
    __builtin_amdgcn_global_load_lds(
        (const __attribute__((address_space(1))) void*)(Bb + (size_t)(wave * 16 + sr) * ldb + colOff),
        (__attribute__((address_space(3))) void*)(ldsB + wave * 1024), 16, 0, 0);
    __builtin_amdgcn_global_load_lds(
        (const __attribute__((address_space(1))) void*)(Bb + (size_t)(64 + wave * 16 + sr) * ldb + colOff),
        (__attribute__((address_space(3))) void*)(ldsB + 4096 + wave * 1024), 16, 0, 0);
  };

  // prologue: both halves of tile 0; land half 0, keep half 1 in flight
  STAGE(0, 0);
  STAGE(0, 1);
  asm volatile("s_waitcnt vmcnt(4)" ::: "memory");
  __builtin_amdgcn_s_barrier();
  __builtin_amdgcn_sched_barrier(0);

  for (int kt = 0; kt < NT; ++kt) {
    const char* bufA = smem + (kt & 1) * 32768;
    const char* bufB = bufA + 16384;
#pragma unroll
    for (int s = 0; s < 2; ++s) {
      bf16x8 afr[4], bfr[4];
#pragma unroll
      for (int m = 0; m < 4; ++m)
        afr[m] = *reinterpret_cast<const bf16x8*>(bufA + s * 8192 + (wr * 4 + m) * 1024 + rd);
#pragma unroll
      for (int n = 0; n < 4; ++n)
        bfr[n] = *reinterpret_cast<const bf16x8*>(bufB + s * 8192 + (wc * 4 + n) * 1024 + rd);
      if (kt + 1 < NT) STAGE(kt + 1, s);
      __builtin_amdgcn_s_barrier();
      __builtin_amdgcn_sched_barrier(0);
      __builtin_amdgcn_s_setprio(1);
#pragma unroll
      for (int m = 0; m < 4; ++m)
#pragma unroll
        for (int n = 0; n < 4; ++n)
          acc[m * 4 + n] = __builtin_amdgcn_mfma_f32_16x16x32_bf16(
              afr[m], bfr[n], acc[m * 4 + n], 0, 0, 0);
      __builtin_amdgcn_s_setprio(0);
      if (kt < NT - 1) {
        asm volatile("s_waitcnt vmcnt(4)" ::: "memory");
      } else if (s == 0) {
        asm volatile("s_waitcnt vmcnt(0)" ::: "memory");
      }
      __builtin_amdgcn_s_barrier();
      __builtin_amdgcn_sched_barrier(0);
    }
  }
}

// ---------------- QKV projection: grid (64,24) = 1536 = 3 exact rounds ----------------
// A = xb [8192][1024], B = Wb [3072][1024]. w = by>>3: 0/1 -> Q/K; 2 -> Vt transposed.
__global__ __launch_bounds__(256, 2) void proj8_kernel(
    const u16* __restrict__ A, const u16* __restrict__ Bm,
    const float* __restrict__ bq, const float* __restrict__ bk,
    const float* __restrict__ bvv, u16* __restrict__ QK, u16* __restrict__ Vt) {
  extern __shared__ char smem[];
  const int tileM = blockIdx.x * 128, tileN = blockIdx.y * 128;
  f32x4 acc[16] = {};
  core128<16>((const char*)A + (size_t)tileM * 2048,
              (const char*)Bm + (size_t)tileN * 2048, 2048, 2048, smem, acc);
  const int tid = threadIdx.x;
  const int wave = tid >> 6, lane = tid & 63;
  const int wr = wave >> 1, wc = wave & 1, fr = lane & 15, fg = lane >> 4;
  const int w = blockIdx.y >> 3;  // weight id (128-col tiles never straddle weights)
  const float* bias = (w == 0) ? bq : (w == 1) ? bk : bvv;
  if (w < 2) {
    u16* O = QK + (size_t)w * 8388608;
#pragma unroll
    for (int mi = 0; mi < 4; ++mi) {
      const int r0 = tileM + wr * 64 + mi * 16 + fg * 4;
#pragma unroll
      for (int n = 0; n < 4; ++n) {
        const int cw = (tileN + wc * 64 + n * 16 + fr) & 1023;
        const float bi = bias[cw];
#pragma unroll
        for (int jj = 0; jj < 4; ++jj)
          O[(size_t)(r0 + jj) * 1024 + cw] = f2b(acc[mi * 4 + n][jj] + bi);
      }
    }
  } else {
#pragma unroll
    for (int mi = 0; mi < 4; ++mi) {
      const int r0 = tileM + wr * 64 + mi * 16 + fg * 4;
      const int b = r0 >> 11, s0 = r0 & 2047;  // rows r0..r0+3 never straddle a batch
#pragma unroll
      for (int n = 0; n < 4; ++n) {
        const int cw = (tileN + wc * 64 + n * 16 + fr) & 1023;
        const float bi = bias[cw];
        ushort4 u = make_ushort4(f2b(acc[mi * 4 + n][0] + bi), f2b(acc[mi * 4 + n][1] + bi),
                                 f2b(acc[mi * 4 + n][2] + bi), f2b(acc[mi * 4 + n][3] + bi));
        *reinterpret_cast<ushort4*>(&Vt[(size_t)b * 2097152 + (size_t)cw * 2048 + s0]) = u;
      }
    }
  }
}

// ---------------- sc: P~ = exp(Q K^T / 32) (bf16) + row-sum partials ----------------
// grid (16,16,4): 128x128 tile per batch z. rowpart[by][z][2048].
__global__ __launch_bounds__(256, 2) void sc8_kernel(const u16* __restrict__ Qb,
                                                     const u16* __restrict__ Kb,
                                                     u16* __restrict__ P,
                                                     float* __restrict__ rowpart) {
  extern __shared__ char smem[];
  const int z = blockIdx.z;
  const int tileM = blockIdx.x * 128, tileN = blockIdx.y * 128;
  f32x4 acc[16] = {};
  core128<16>((const char*)Qb + (size_t)z * 4194304 + (size_t)tileM * 2048,
              (const char*)Kb + (size_t)z * 4194304 + (size_t)tileN * 2048, 2048, 2048,
              smem, acc);
  const int tid = threadIdx.x;
  const int wave = tid >> 6, lane = tid & 63;
  const int wr = wave >> 1, wc = wave & 1, fr = lane & 15, fg = lane >> 4;
  float* rs = (float*)smem;  // [2][128]; safe: core128 ends with full barrier
  u16* Po = P + (size_t)z * 4194304 + (size_t)tileM * 2048 + tileN;
#pragma unroll
  for (int mi = 0; mi < 4; ++mi) {
#pragma unroll
    for (int jj = 0; jj < 4; ++jj) {
      const int rl = wr * 64 + mi * 16 + fg * 4 + jj;
      float part = 0.f;
#pragma unroll
      for (int n = 0; n < 4; ++n) {
        float e = __expf(acc[mi * 4 + n][jj] * 0.03125f);
        part += e;
        Po[(size_t)rl * 2048 + wc * 64 + n * 16 + fr] = f2b(e);
      }
      part += __shfl_xor(part, 1);
      part += __shfl_xor(part, 2);
      part += __shfl_xor(part, 4);
      part += __shfl_xor(part, 8);
      if (fr == 0) rs[wc * 128 + rl] = part;
    }
  }
  __syncthreads();
  if (tid < 128) {
    float s = rs[tid] + rs[128 + tid];
    rowpart[(size_t)blockIdx.y * 8192 + z * 2048 + tileM + tid] = s;
  }
}

// ---------------- pv: out = (P~ Vt^T) * rowinv (rowinv computed in-kernel) ----------------
// grid (16,8,4): tileM = bx*128, tileN = by*128, z = batch. NT=32.
__global__ __launch_bounds__(256, 2) void pv8_kernel(const u16* __restrict__ P,
                                                     const u16* __restrict__ Vt,
                                                     const float* __restrict__ rowpart,
                                                     float* __restrict__ out) {
  extern __shared__ char smem[];  // 65536 core + 512 rowinv
  const int z = blockIdx.z;
  const int tileM = blockIdx.x * 128, tileN = blockIdx.y * 128;
  float* rinv = (float*)(smem + 65536);
  const int tid = threadIdx.x;
  if (tid < 128) {
    float s = 0.f;
#pragma unroll
    for (int t = 0; t < 16; ++t) s += rowpart[t * 8192 + z * 2048 + tileM + tid];
    rinv[tid] = 1.0f / s;
  }
  __builtin_amdgcn_sched_barrier(0);
  // core128's first barrier orders the rinv write before epilogue reads.
  f32x4 acc[16] = {};
  core128<32>((const char*)P + (size_t)z * 8388608 + (size_t)tileM * 4096,
              (const char*)Vt + (size_t)z * 4194304 + (size_t)tileN * 4096, 4096, 4096,
              smem, acc);
  const int wave = tid >> 6, lane = tid & 63;
  const int wr = wave >> 1, wc = wave & 1, fr = lane & 15, fg = lane >> 4;
  float* O = out + (size_t)z * 2097152;
#pragma unroll
  for (int mi = 0; mi < 4; ++mi) {
#pragma unroll
    for (int jj = 0; jj < 4; ++jj) {
      const int r = wr * 64 + mi * 16 + fg * 4 + jj;
      const float inv = rinv[r];
#pragma unroll
      for (int n = 0; n < 4; ++n)
        O[(size_t)(tileM + r) * 1024 + tileN + wc * 64 + n * 16 + fr] =
            acc[mi * 4 + n][jj] * inv;
    }
  }
}

extern "C" void kernel_launch(void* const* d_in, const int* in_sizes, int n_in,
                              void* d_out, int out_size, void* d_ws, size_t ws_size,
                              hipStream_t stream) {
  if (ws_size < ((size_t)72 << 20)) return;
  const float* x = (const float*)d_in[0];
  const float* Wq = (const float*)d_in[1];
  const float* bq = (const float*)d_in[2];
  const float* Wk = (const float*)d_in[3];
  const float* bk = (const float*)d_in[4];
  const float* Wv = (const float*)d_in[5];
  const float* bv = (const float*)d_in[6];
  char* ws = (char*)d_ws;
  u16* xb = (u16*)(ws);                       // [0,16M); later P~ [4][2048][2048]
  u16* Pb = (u16*)(ws);
  u16* Qb = (u16*)(ws + ((size_t)16 << 20));
  u16* Kb = (u16*)(ws + ((size_t)32 << 20));
  u16* Vt = (u16*)(ws + ((size_t)48 << 20));
  u16* Wb = (u16*)(ws + ((size_t)64 << 20));
  float* rowpart = (float*)(ws + ((size_t)70 << 20));  // 512 KiB
  float* out = (float*)d_out;

  (void)hipFuncSetAttribute((const void*)proj8_kernel,
                            hipFuncAttributeMaxDynamicSharedMemorySize, 65536);
  (void)hipFuncSetAttribute((const void*)sc8_kernel,
                            hipFuncAttributeMaxDynamicSharedMemorySize, 65536);
  (void)hipFuncSetAttribute((const void*)pv8_kernel,
                            hipFuncAttributeMaxDynamicSharedMemorySize, 66048);

  cast_all_kernel<<<11264, 256, 0, stream>>>(x, Wq, Wk, Wv, xb, Wb);

  proj8_kernel<<<dim3(64, 24), 256, 65536, stream>>>(xb, Wb, bq, bk, bv, Qb, Vt);

  sc8_kernel<<<dim3(16, 16, 4), 256, 65536, stream>>>(Qb, Kb, Pb, rowpart);
  pv8_kernel<<<dim3(16, 8, 4), 256, 66048, stream>>>(Pb, Vt, rowpart, out);
}

// Round 10
// 157.121 us; speedup vs baseline: 1.0663x; 1.0663x over previous
//
#include <hip/hip_runtime.h>

// SelfAttention: B=4, S=2048, D=1024, fp32 in/out. bf16 MFMA, fp32 accum.
// R9: pipelined-read core2p. Phase = [STAGE next-half; counted vmcnt; barrier;
// ds_read frags for NEXT phase; sched_barrier; MFMA on PREV-read frags; barrier].
// MFMA never waits on same-phase ds_reads (they overlap the MFMA cluster).
// Stage cadence: G(kt+1,1) issued @ phase(kt,0), G(kt+2,0) @ phase(kt,1);
// steady waits vmcnt(2 groups); tails vmcnt(1g)/vmcnt(0). Double-buffered.
// GEOM1 pipelines A+B frags; GEOM0 pipelines A only (B read in-phase ahead of
// the A-next burst -> implicit lgkmcnt(8), keeps VGPR < 256).
//   proj: 128x256 GEOM1, grid (64,12) = 768 = 3 exact rounds
//   sc:   256x256 GEOM0, grid (8,8,4) = 256, P~=exp(QK^T/32)+rowsums
//   pv:   128x256 GEOM1, grid (16,4,4) = 256, * 1/rowsum (in-kernel rsum)
// ws layout (MiB):
//   [0,16)   x_bf16 (proj) -> P~ bf16 [4][2048][2048]
//   [16,32)  Q bf16   [32,48) K bf16   [48,64) Vt bf16 [4][1024][2048]
//   [64,70)  Wq|Wk|Wv bf16
//   [70,+256K) rowpart fp32 [8][4][2048]

typedef __bf16 bf16x8 __attribute__((ext_vector_type(8)));
typedef float f32x4 __attribute__((ext_vector_type(4)));
typedef unsigned short u16;

__device__ __forceinline__ u16 f2b(float f) {
  union { float f; unsigned u; } a; a.f = f;
  unsigned r = a.u + 0x7fffu + ((a.u >> 16) & 1u);  // RNE
  return (u16)(r >> 16);
}

// blocks [0,8192): x (2097152 float4s). blocks [8192,11264): Wq|Wk|Wv.
__global__ __launch_bounds__(256) void cast_all_kernel(const float* __restrict__ x,
                                                       const float* __restrict__ Wq,
                                                       const float* __restrict__ Wk,
                                                       const float* __restrict__ Wv,
                                                       u16* __restrict__ xb,
                                                       u16* __restrict__ Wb) {
  int b = blockIdx.x;
  if (b < 8192) {
    const int i = b * 256 + threadIdx.x;
    float4 v = reinterpret_cast<const float4*>(x)[i];
    reinterpret_cast<ushort4*>(xb)[i] =
        make_ushort4(f2b(v.x), f2b(v.y), f2b(v.z), f2b(v.w));
  } else {
    b -= 8192;
    const int w = b >> 10;
    const float* src = (w == 0) ? Wq : (w == 1) ? Wk : Wv;
    const int i = (b & 1023) * 256 + threadIdx.x;
    float4 v = reinterpret_cast<const float4*>(src)[i];
    reinterpret_cast<ushort4*>(Wb + (size_t)w * 1048576)[i] =
        make_ushort4(f2b(v.x), f2b(v.y), f2b(v.z), f2b(v.w));
  }
}

#define VMCNT(n) asm volatile("s_waitcnt vmcnt(" #n ")" ::: "memory")

// ---------------- pipelined-read merged-phase core (R9) ----------------
// GEOM 0: BM=256,BN=256, acc f32x4[32], stage group = 4 loads.
// GEOM 1: BM=128,BN=256, acc f32x4[16], stage group = 3 loads.
// 8 waves: wr=wave>>2 (M), wc=wave&3 (N). BK=64, NT K-tiles, lda/ldb in BYTES.
template <int GEOM, int NT>
__device__ __forceinline__ void core2p(const char* __restrict__ Ab,
                                       const char* __restrict__ Bb, int lda, int ldb,
                                       char* smem, f32x4* acc) {
  constexpr int LDSBUF = GEOM ? 49152 : 65536;
  constexpr int BOFF = GEOM ? 16384 : 32768;
  constexpr int AHALF = GEOM ? 8192 : 16384;
  constexpr int NA = GEOM ? 4 : 8;  // A frags per phase
  const int tid = threadIdx.x;
  const int wave = tid >> 6, lane = tid & 63;
  const int wr = wave >> 2, wc = wave & 3;
  const int fr = lane & 15, fg = lane >> 4;
  const int rd = (fr * 64 + fg * 16) ^ (((fr >> 3) & 1) << 5);
  const int li = (lane * 16) ^ ((lane >> 5) << 5);
  const int sr = li >> 6, sc2 = li & 63;

  auto STAGE = [&](int kt, int s) {  // A-half s + B-half s of tile kt
    char* base = smem + (kt & 1) * LDSBUF;
    const int colOff = kt * 128 + s * 64 + sc2;
    char* ldsA = base + s * AHALF;
    __builtin_amdgcn_global_load_lds(
        (const __attribute__((address_space(1))) void*)(Ab + (size_t)(wave * 16 + sr) * lda + colOff),
        (__attribute__((address_space(3))) void*)(ldsA + wave * 1024), 16, 0, 0);
    if constexpr (GEOM == 0)
      __builtin_amdgcn_global_load_lds(
          (const __attribute__((address_space(1))) void*)(Ab + (size_t)((8 + wave) * 16 + sr) * lda + colOff),
          (__attribute__((address_space(3))) void*)(ldsA + 8192 + wave * 1024), 16, 0, 0);
    char* ldsB = base + BOFF + s * 16384;
    __builtin_amdgcn_global_load_lds(
        (const __attribute__((address_space(1))) void*)(Bb + (size_t)(wave * 16 + sr) * ldb + colOff),
        (__attribute__((address_space(3))) void*)(ldsB + wave * 1024), 16, 0, 0);
    __builtin_amdgcn_global_load_lds(
        (const __attribute__((address_space(1))) void*)(Bb + (size_t)((8 + wave) * 16 + sr) * ldb + colOff),
        (__attribute__((address_space(3))) void*)(ldsB + 8192 + wave * 1024), 16, 0, 0);
  };
  auto RD_A = [&](const char* buf, int s, bf16x8* a) {
#pragma unroll
    for (int m = 0; m < NA; ++m)
      a[m] = *reinterpret_cast<const bf16x8*>(buf + s * AHALF + (wr * NA + m) * 1024 + rd);
  };
  auto RD_B = [&](const char* buf, int s, bf16x8* b) {
#pragma unroll
    for (int n = 0; n < 4; ++n)
      b[n] = *reinterpret_cast<const bf16x8*>(buf + BOFF + s * 16384 + (wc * 4 + n) * 1024 + rd);
  };
  auto MFMA = [&](bf16x8* a, bf16x8* b) {
    __builtin_amdgcn_s_setprio(1);
#pragma unroll
    for (int m = 0; m < NA; ++m)
#pragma unroll
      for (int n = 0; n < 4; ++n)
        acc[m * 4 + n] = __builtin_amdgcn_mfma_f32_16x16x32_bf16(a[m], b[n], acc[m * 4 + n], 0, 0, 0);
    __builtin_amdgcn_s_setprio(0);
  };

  // prologue: 3 stage groups out; land G(0,0); pre-read its frags
  STAGE(0, 0);
  STAGE(0, 1);
  STAGE(1, 0);
  if constexpr (GEOM == 0) VMCNT(8); else VMCNT(6);
  __builtin_amdgcn_s_barrier();
  __builtin_amdgcn_sched_barrier(0);

  bf16x8 a0[NA], a1[NA], b0[4], b1[4];
  RD_A(smem, 0, a0);
  if constexpr (GEOM == 1) RD_B(smem, 0, b0);

  for (int kt = 0; kt < NT; ++kt) {
    const char* buf = smem + (kt & 1) * LDSBUF;
    const char* bufN = smem + ((kt + 1) & 1) * LDSBUF;
    // ---- phase 0: consume (kt,0); pre-read (kt,1) ----
    if (kt + 1 < NT) STAGE(kt + 1, 1);
    if (kt < NT - 1) { if constexpr (GEOM == 0) VMCNT(8); else VMCNT(6); }
    else VMCNT(0);
    __builtin_amdgcn_s_barrier();
    if constexpr (GEOM == 0) RD_B(buf, 0, b0);  // B for THIS phase (lands via lgkmcnt(8))
    RD_A(buf, 1, a1);
    if constexpr (GEOM == 1) RD_B(buf, 1, b1);
    __builtin_amdgcn_sched_barrier(0);
    MFMA(a0, b0);
    __builtin_amdgcn_s_barrier();
    // ---- phase 1: consume (kt,1); pre-read (kt+1,0) ----
    if (kt + 2 < NT) STAGE(kt + 2, 0);
    if (kt < NT - 1) {
      if (kt < NT - 2) { if constexpr (GEOM == 0) VMCNT(8); else VMCNT(6); }
      else             { if constexpr (GEOM == 0) VMCNT(4); else VMCNT(3); }
      __builtin_amdgcn_s_barrier();
      if constexpr (GEOM == 0) RD_B(buf, 1, b1);
      RD_A(bufN, 0, a0);
      if constexpr (GEOM == 1) RD_B(bufN, 0, b0);
      __builtin_amdgcn_sched_barrier(0);
      MFMA(a1, b1);
    } else {
      __builtin_amdgcn_s_barrier();
      if constexpr (GEOM == 0) RD_B(buf, 1, b1);
      __builtin_amdgcn_sched_barrier(0);
      MFMA(a1, b1);
    }
    __builtin_amdgcn_s_barrier();
  }
}

// ---------------- QKV projection: GEOM1, grid (64,12) = 768 = 3 exact rounds ----------------
// A = xb [8192][1024], B = Wb [3072][1024]. w = by>>2: 0/1 -> Q/K; 2 -> Vt transposed.
__global__ __launch_bounds__(512, 2) void proj8_kernel(
    const u16* __restrict__ A, const u16* __restrict__ Bm,
    const float* __restrict__ bq, const float* __restrict__ bk,
    const float* __restrict__ bvv, u16* __restrict__ QK, u16* __restrict__ Vt) {
  extern __shared__ char smem[];
  const int tileM = blockIdx.x * 128, tileN = blockIdx.y * 256;
  f32x4 acc[16] = {};
  core2p<1, 16>((const char*)A + (size_t)tileM * 2048,
                (const char*)Bm + (size_t)tileN * 2048, 2048, 2048, smem, acc);
  const int tid = threadIdx.x;
  const int wave = tid >> 6, lane = tid & 63;
  const int wr = wave >> 2, wc = wave & 3, fr = lane & 15, fg = lane >> 4;
  const int w = blockIdx.y >> 2;  // weight id (256-col tiles never straddle weights)
  const float* bias = (w == 0) ? bq : (w == 1) ? bk : bvv;
  if (w < 2) {
    u16* O = QK + (size_t)w * 8388608;
#pragma unroll
    for (int mi = 0; mi < 4; ++mi) {
      const int r0 = tileM + wr * 64 + mi * 16 + fg * 4;
#pragma unroll
      for (int n = 0; n < 4; ++n) {
        const int cw = (tileN + wc * 64 + n * 16 + fr) & 1023;
        const float bi = bias[cw];
#pragma unroll
        for (int jj = 0; jj < 4; ++jj)
          O[(size_t)(r0 + jj) * 1024 + cw] = f2b(acc[mi * 4 + n][jj] + bi);
      }
    }
  } else {
#pragma unroll
    for (int mi = 0; mi < 4; ++mi) {
      const int r0 = tileM + wr * 64 + mi * 16 + fg * 4;
      const int b = r0 >> 11, s0 = r0 & 2047;  // rows r0..r0+3 never straddle a batch
#pragma unroll
      for (int n = 0; n < 4; ++n) {
        const int cw = (tileN + wc * 64 + n * 16 + fr) & 1023;
        const float bi = bias[cw];
        ushort4 u = make_ushort4(f2b(acc[mi * 4 + n][0] + bi), f2b(acc[mi * 4 + n][1] + bi),
                                 f2b(acc[mi * 4 + n][2] + bi), f2b(acc[mi * 4 + n][3] + bi));
        *reinterpret_cast<ushort4*>(&Vt[(size_t)b * 2097152 + (size_t)cw * 2048 + s0]) = u;
      }
    }
  }
}

// ---------------- sc: P~ = exp(Q K^T / 32) (bf16) + row-sum partials ----------------
__global__ __launch_bounds__(512, 2) void sc8_kernel(const u16* __restrict__ Qb,
                                                     const u16* __restrict__ Kb,
                                                     u16* __restrict__ P,
                                                     float* __restrict__ rowpart) {
  extern __shared__ char smem[];
  const int z = blockIdx.z;
  const int tileM = blockIdx.x * 256, tileN = blockIdx.y * 256;
  f32x4 acc[32] = {};
  core2p<0, 16>((const char*)Qb + (size_t)z * 4194304 + (size_t)tileM * 2048,
                (const char*)Kb + (size_t)z * 4194304 + (size_t)tileN * 2048, 2048, 2048,
                smem, acc);
  const int tid = threadIdx.x;
  const int wave = tid >> 6, lane = tid & 63;
  const int wr = wave >> 2, wc = wave & 3, fr = lane & 15, fg = lane >> 4;
  float* rs = (float*)smem;  // [4][256]; safe: core2p ends with full barrier
  u16* Po = P + (size_t)z * 4194304 + (size_t)tileM * 2048 + tileN;
#pragma unroll
  for (int mi = 0; mi < 8; ++mi) {
#pragma unroll
    for (int jj = 0; jj < 4; ++jj) {
      const int rl = wr * 128 + mi * 16 + fg * 4 + jj;
      float part = 0.f;
#pragma unroll
      for (int n = 0; n < 4; ++n) {
        float e = __expf(acc[mi * 4 + n][jj] * 0.03125f);
        part += e;
        Po[(size_t)rl * 2048 + wc * 64 + n * 16 + fr] = f2b(e);
      }
      part += __shfl_xor(part, 1);
      part += __shfl_xor(part, 2);
      part += __shfl_xor(part, 4);
      part += __shfl_xor(part, 8);
      if (fr == 0) rs[wc * 256 + rl] = part;
    }
  }
  __syncthreads();
  if (tid < 256) {
    float s = rs[tid] + rs[256 + tid] + rs[512 + tid] + rs[768 + tid];
    rowpart[(size_t)blockIdx.y * 8192 + z * 2048 + tileM + tid] = s;
  }
}

// ---------------- pv: out = (P~ Vt^T) * rowinv (rowinv computed in-kernel) ----------------
__global__ __launch_bounds__(512, 2) void pv8_kernel(const u16* __restrict__ P,
                                                     const u16* __restrict__ Vt,
                                                     const float* __restrict__ rowpart,
                                                     float* __restrict__ out) {
  extern __shared__ char smem[];  // 98304 core + 512 rowinv
  const int z = blockIdx.z;
  const int tileM = blockIdx.x * 128, tileN = blockIdx.y * 256;
  float* rinv = (float*)(smem + 98304);
  const int tid = threadIdx.x;
  if (tid < 128) {
    float s = 0.f;
#pragma unroll
    for (int t = 0; t < 8; ++t) s += rowpart[t * 8192 + z * 2048 + tileM + tid];
    rinv[tid] = 1.0f / s;
  }
  __builtin_amdgcn_sched_barrier(0);  // pin rinv loads/stores before staging
  // core2p's barriers order the rinv write before epilogue reads.
  f32x4 acc[16] = {};
  core2p<1, 32>((const char*)P + (size_t)z * 8388608 + (size_t)tileM * 4096,
                (const char*)Vt + (size_t)z * 4194304 + (size_t)tileN * 4096, 4096, 4096,
                smem, acc);
  const int wave = tid >> 6, lane = tid & 63;
  const int wr = wave >> 2, wc = wave & 3, fr = lane & 15, fg = lane >> 4;
  float* O = out + (size_t)z * 2097152;
#pragma unroll
  for (int mi = 0; mi < 4; ++mi) {
#pragma unroll
    for (int jj = 0; jj < 4; ++jj) {
      const int r = wr * 64 + mi * 16 + fg * 4 + jj;
      const float inv = rinv[r];
#pragma unroll
      for (int n = 0; n < 4; ++n)
        O[(size_t)(tileM + r) * 1024 + tileN + wc * 64 + n * 16 + fr] =
            acc[mi * 4 + n][jj] * inv;
    }
  }
}

extern "C" void kernel_launch(void* const* d_in, const int* in_sizes, int n_in,
                              void* d_out, int out_size, void* d_ws, size_t ws_size,
                              hipStream_t stream) {
  if (ws_size < ((size_t)72 << 20)) return;
  const float* x = (const float*)d_in[0];
  const float* Wq = (const float*)d_in[1];
  const float* bq = (const float*)d_in[2];
  const float* Wk = (const float*)d_in[3];
  const float* bk = (const float*)d_in[4];
  const float* Wv = (const float*)d_in[5];
  const float* bv = (const float*)d_in[6];
  char* ws = (char*)d_ws;
  u16* xb = (u16*)(ws);                       // [0,16M); later P~ [4][2048][2048]
  u16* Pb = (u16*)(ws);
  u16* Qb = (u16*)(ws + ((size_t)16 << 20));
  u16* Kb = (u16*)(ws + ((size_t)32 << 20));
  u16* Vt = (u16*)(ws + ((size_t)48 << 20));
  u16* Wb = (u16*)(ws + ((size_t)64 << 20));
  float* rowpart = (float*)(ws + ((size_t)70 << 20));  // 256 KiB
  float* out = (float*)d_out;

  (void)hipFuncSetAttribute((const void*)proj8_kernel,
                            hipFuncAttributeMaxDynamicSharedMemorySize, 98304);
  (void)hipFuncSetAttribute((const void*)sc8_kernel,
                            hipFuncAttributeMaxDynamicSharedMemorySize, 131072);
  (void)hipFuncSetAttribute((const void*)pv8_kernel,
                            hipFuncAttributeMaxDynamicSharedMemorySize, 98816);

  cast_all_kernel<<<11264, 256, 0, stream>>>(x, Wq, Wk, Wv, xb, Wb);

  proj8_kernel<<<dim3(64, 12), 512, 98304, stream>>>(xb, Wb, bq, bk, bv, Qb, Vt);

  sc8_kernel<<<dim3(8, 8, 4), 512, 131072, stream>>>(Qb, Kb, Pb, rowpart);
  pv8_kernel<<<dim3(16, 4, 4), 512, 98816, stream>>>(Pb, Vt, rowpart, out);
}

// Round 11
// 155.925 us; speedup vs baseline: 1.0745x; 1.0077x over previous
//
#include <hip/hip_runtime.h>

// SelfAttention: B=4, S=2048, D=1024, fp32 in/out. bf16 MFMA, fp32 accum.
// R10: phase-content law (see R10 notes): a phase costs ~825cyc per 16-MFMA
// quantum with ~1650 floor -> GEOM0 (32 MFMA/phase) runs 63% busy-CU, GEOM1 31%.
// proj split into two exact-fill dispatches:
//   qkproj: core2 GEOM0 256x256, grid (32,8) = 256 blocks (Q and K)
//   vproj:  core2 GEOM1 128x256, grid (64,4) = 256 blocks (Vt transposed)
//   sc:     core2 GEOM0, grid (8,8,4) = 256, P~=exp(QK^T/32)+rowsums
//   pv:     core2 GEOM1, grid (16,4,4) = 256, * 1/rowsum (in-kernel rsum)
// ws layout (MiB):
//   [0,16)   x_bf16 (proj) -> P~ bf16 [4][2048][2048]
//   [16,32)  Q bf16   [32,48) K bf16   [48,64) Vt bf16 [4][1024][2048]
//   [64,70)  Wq|Wk|Wv bf16
//   [70,+256K) rowpart fp32 [8][4][2048]

typedef __bf16 bf16x8 __attribute__((ext_vector_type(8)));
typedef float f32x4 __attribute__((ext_vector_type(4)));
typedef unsigned short u16;

__device__ __forceinline__ u16 f2b(float f) {
  union { float f; unsigned u; } a; a.f = f;
  unsigned r = a.u + 0x7fffu + ((a.u >> 16) & 1u);  // RNE
  return (u16)(r >> 16);
}

// blocks [0,8192): x (2097152 float4s). blocks [8192,11264): Wq|Wk|Wv.
__global__ __launch_bounds__(256) void cast_all_kernel(const float* __restrict__ x,
                                                       const float* __restrict__ Wq,
                                                       const float* __restrict__ Wk,
                                                       const float* __restrict__ Wv,
                                                       u16* __restrict__ xb,
                                                       u16* __restrict__ Wb) {
  int b = blockIdx.x;
  if (b < 8192) {
    const int i = b * 256 + threadIdx.x;
    float4 v = reinterpret_cast<const float4*>(x)[i];
    reinterpret_cast<ushort4*>(xb)[i] =
        make_ushort4(f2b(v.x), f2b(v.y), f2b(v.z), f2b(v.w));
  } else {
    b -= 8192;
    const int w = b >> 10;
    const float* src = (w == 0) ? Wq : (w == 1) ? Wk : Wv;
    const int i = (b & 1023) * 256 + threadIdx.x;
    float4 v = reinterpret_cast<const float4*>(src)[i];
    reinterpret_cast<ushort4*>(Wb + (size_t)w * 1048576)[i] =
        make_ushort4(f2b(v.x), f2b(v.y), f2b(v.z), f2b(v.w));
  }
}

// ---------------- merged-phase double-buffered core (R7, validated) ----------------
// GEOM 0: BM=256,BN=256, acc f32x4[32]; GEOM 1: BM=128,BN=256, acc f32x4[16].
// 8 waves: wr=wave>>2 (M), wc=wave&3 (N). BK=64, NT K-tiles. lda/ldb in BYTES.
template <int GEOM, int NT>
__device__ __forceinline__ void core2(const char* __restrict__ Ab,
                                      const char* __restrict__ Bb, int lda, int ldb,
                                      char* smem, f32x4* acc) {
  constexpr int LDSBUF = GEOM ? 49152 : 65536;
  constexpr int BOFF = GEOM ? 16384 : 32768;
  constexpr int AHALF = GEOM ? 8192 : 16384;
  constexpr int NA = GEOM ? 4 : 8;  // A fragments per phase
  const int tid = threadIdx.x;
  const int wave = tid >> 6, lane = tid & 63;
  const int wr = wave >> 2, wc = wave & 3;
  const int fr = lane & 15, fg = lane >> 4;
  const int rd = (fr * 64 + fg * 16) ^ (((fr >> 3) & 1) << 5);
  const int li = (lane * 16) ^ ((lane >> 5) << 5);
  const int sr = li >> 6, sc2 = li & 63;

  auto STAGE = [&](int kt, int s) {  // A-half s + B-half s of tile kt
    char* base = smem + (kt & 1) * LDSBUF;
    const int colOff = kt * 128 + s * 64 + sc2;
    char* ldsA = base + s * AHALF;
    __builtin_amdgcn_global_load_lds(
        (const __attribute__((address_space(1))) void*)(Ab + (size_t)(wave * 16 + sr) * lda + colOff),
        (__attribute__((address_space(3))) void*)(ldsA + wave * 1024), 16, 0, 0);
    if constexpr (GEOM == 0)
      __builtin_amdgcn_global_load_lds(
          (const __attribute__((address_space(1))) void*)(Ab + (size_t)((8 + wave) * 16 + sr) * lda + colOff),
          (__attribute__((address_space(3))) void*)(ldsA + 8192 + wave * 1024), 16, 0, 0);
    char* ldsB = base + BOFF + s * 16384;
    __builtin_amdgcn_global_load_lds(
        (const __attribute__((address_space(1))) void*)(Bb + (size_t)(wave * 16 + sr) * ldb + colOff),
        (__attribute__((address_space(3))) void*)(ldsB + wave * 1024), 16, 0, 0);
    __builtin_amdgcn_global_load_lds(
        (const __attribute__((address_space(1))) void*)(Bb + (size_t)((8 + wave) * 16 + sr) * ldb + colOff),
        (__attribute__((address_space(3))) void*)(ldsB + 8192 + wave * 1024), 16, 0, 0);
  };

  // prologue: both halves of tile 0; land half 0, keep half 1 in flight
  STAGE(0, 0);
  STAGE(0, 1);
  if constexpr (GEOM == 0) asm volatile("s_waitcnt vmcnt(4)" ::: "memory");
  else asm volatile("s_waitcnt vmcnt(3)" ::: "memory");
  __builtin_amdgcn_s_barrier();
  __builtin_amdgcn_sched_barrier(0);

  for (int kt = 0; kt < NT; ++kt) {
    const char* bufA = smem + (kt & 1) * LDSBUF;
    const char* bufB = bufA + BOFF;
#pragma unroll
    for (int s = 0; s < 2; ++s) {
      bf16x8 afr[NA], bfr[4];
#pragma unroll
      for (int m = 0; m < NA; ++m)
        afr[m] = *reinterpret_cast<const bf16x8*>(bufA + s * AHALF + (wr * NA + m) * 1024 + rd);
#pragma unroll
      for (int n = 0; n < 4; ++n)
        bfr[n] = *reinterpret_cast<const bf16x8*>(bufB + s * 16384 + (wc * 4 + n) * 1024 + rd);
      if (kt + 1 < NT) STAGE(kt + 1, s);
      __builtin_amdgcn_s_barrier();
      __builtin_amdgcn_sched_barrier(0);
      __builtin_amdgcn_s_setprio(1);
#pragma unroll
      for (int m = 0; m < NA; ++m)
#pragma unroll
        for (int n = 0; n < 4; ++n)
          acc[m * 4 + n] = __builtin_amdgcn_mfma_f32_16x16x32_bf16(
              afr[m], bfr[n], acc[m * 4 + n], 0, 0, 0);
      __builtin_amdgcn_s_setprio(0);
      if (kt < NT - 1) {
        if constexpr (GEOM == 0) asm volatile("s_waitcnt vmcnt(4)" ::: "memory");
        else asm volatile("s_waitcnt vmcnt(3)" ::: "memory");
      } else if (s == 0) {
        asm volatile("s_waitcnt vmcnt(0)" ::: "memory");
      }
      __builtin_amdgcn_s_barrier();
      __builtin_amdgcn_sched_barrier(0);
    }
  }
}

// ---------------- QK projection: GEOM0 256x256, grid (32,8) = 256 exact ----------------
// A = xb [8192][1024], B = Wb[Wq|Wk] [2048][1024]. w = by>>2: 0 -> Q, 1 -> K.
__global__ __launch_bounds__(512, 2) void qkproj_kernel(
    const u16* __restrict__ A, const u16* __restrict__ Bm,
    const float* __restrict__ bq, const float* __restrict__ bk,
    u16* __restrict__ QK) {
  extern __shared__ char smem[];
  const int tileM = blockIdx.x * 256, tileN = blockIdx.y * 256;
  f32x4 acc[32] = {};
  core2<0, 16>((const char*)A + (size_t)tileM * 2048,
               (const char*)Bm + (size_t)tileN * 2048, 2048, 2048, smem, acc);
  const int tid = threadIdx.x;
  const int wave = tid >> 6, lane = tid & 63;
  const int wr = wave >> 2, wc = wave & 3, fr = lane & 15, fg = lane >> 4;
  const int w = blockIdx.y >> 2;  // 0 -> Q, 1 -> K (256-col tiles never straddle)
  const float* bias = (w == 0) ? bq : bk;
  u16* O = QK + (size_t)w * 8388608;
#pragma unroll
  for (int mi = 0; mi < 8; ++mi) {
    const int r0 = tileM + wr * 128 + mi * 16 + fg * 4;
#pragma unroll
    for (int n = 0; n < 4; ++n) {
      const int cw = (tileN + wc * 64 + n * 16 + fr) & 1023;
      const float bi = bias[cw];
#pragma unroll
      for (int jj = 0; jj < 4; ++jj)
        O[(size_t)(r0 + jj) * 1024 + cw] = f2b(acc[mi * 4 + n][jj] + bi);
    }
  }
}

// ---------------- V projection: GEOM1 128x256, grid (64,4) = 256 exact ----------------
// A = xb [8192][1024], B = Wv_b16 [1024][1024]. Output Vt [4][1024][2048] transposed.
__global__ __launch_bounds__(512, 2) void vproj_kernel(
    const u16* __restrict__ A, const u16* __restrict__ Bv,
    const float* __restrict__ bvv, u16* __restrict__ Vt) {
  extern __shared__ char smem[];
  const int tileM = blockIdx.x * 128, tileN = blockIdx.y * 256;
  f32x4 acc[16] = {};
  core2<1, 16>((const char*)A + (size_t)tileM * 2048,
               (const char*)Bv + (size_t)tileN * 2048, 2048, 2048, smem, acc);
  const int tid = threadIdx.x;
  const int wave = tid >> 6, lane = tid & 63;
  const int wr = wave >> 2, wc = wave & 3, fr = lane & 15, fg = lane >> 4;
#pragma unroll
  for (int mi = 0; mi < 4; ++mi) {
    const int r0 = tileM + wr * 64 + mi * 16 + fg * 4;
    const int b = r0 >> 11, s0 = r0 & 2047;  // rows r0..r0+3 never straddle a batch
#pragma unroll
    for (int n = 0; n < 4; ++n) {
      const int cw = (tileN + wc * 64 + n * 16 + fr) & 1023;
      const float bi = bvv[cw];
      ushort4 u = make_ushort4(f2b(acc[mi * 4 + n][0] + bi), f2b(acc[mi * 4 + n][1] + bi),
                               f2b(acc[mi * 4 + n][2] + bi), f2b(acc[mi * 4 + n][3] + bi));
      *reinterpret_cast<ushort4*>(&Vt[(size_t)b * 2097152 + (size_t)cw * 2048 + s0]) = u;
    }
  }
}

// ---------------- sc: P~ = exp(Q K^T / 32) (bf16) + row-sum partials ----------------
__global__ __launch_bounds__(512, 2) void sc8_kernel(const u16* __restrict__ Qb,
                                                     const u16* __restrict__ Kb,
                                                     u16* __restrict__ P,
                                                     float* __restrict__ rowpart) {
  extern __shared__ char smem[];
  const int z = blockIdx.z;
  const int tileM = blockIdx.x * 256, tileN = blockIdx.y * 256;
  f32x4 acc[32] = {};
  core2<0, 16>((const char*)Qb + (size_t)z * 4194304 + (size_t)tileM * 2048,
               (const char*)Kb + (size_t)z * 4194304 + (size_t)tileN * 2048, 2048, 2048,
               smem, acc);
  const int tid = threadIdx.x;
  const int wave = tid >> 6, lane = tid & 63;
  const int wr = wave >> 2, wc = wave & 3, fr = lane & 15, fg = lane >> 4;
  float* rs = (float*)smem;  // [4][256]; safe: core2 ends with full barrier
  u16* Po = P + (size_t)z * 4194304 + (size_t)tileM * 2048 + tileN;
#pragma unroll
  for (int mi = 0; mi < 8; ++mi) {
#pragma unroll
    for (int jj = 0; jj < 4; ++jj) {
      const int rl = wr * 128 + mi * 16 + fg * 4 + jj;
      float part = 0.f;
#pragma unroll
      for (int n = 0; n < 4; ++n) {
        float e = __expf(acc[mi * 4 + n][jj] * 0.03125f);
        part += e;
        Po[(size_t)rl * 2048 + wc * 64 + n * 16 + fr] = f2b(e);
      }
      part += __shfl_xor(part, 1);
      part += __shfl_xor(part, 2);
      part += __shfl_xor(part, 4);
      part += __shfl_xor(part, 8);
      if (fr == 0) rs[wc * 256 + rl] = part;
    }
  }
  __syncthreads();
  if (tid < 256) {
    float s = rs[tid] + rs[256 + tid] + rs[512 + tid] + rs[768 + tid];
    rowpart[(size_t)blockIdx.y * 8192 + z * 2048 + tileM + tid] = s;
  }
}

// ---------------- pv: out = (P~ Vt^T) * rowinv (rowinv computed in-kernel) ----------------
__global__ __launch_bounds__(512, 2) void pv8_kernel(const u16* __restrict__ P,
                                                     const u16* __restrict__ Vt,
                                                     const float* __restrict__ rowpart,
                                                     float* __restrict__ out) {
  extern __shared__ char smem[];  // 98304 core + 512 rowinv
  const int z = blockIdx.z;
  const int tileM = blockIdx.x * 128, tileN = blockIdx.y * 256;
  float* rinv = (float*)(smem + 98304);
  const int tid = threadIdx.x;
  if (tid < 128) {
    float s = 0.f;
#pragma unroll
    for (int t = 0; t < 8; ++t) s += rowpart[t * 8192 + z * 2048 + tileM + tid];
    rinv[tid] = 1.0f / s;
  }
  __builtin_amdgcn_sched_barrier(0);  // pin rinv loads/stores before staging
  // core2's first barrier orders the rinv write before epilogue reads.
  f32x4 acc[16] = {};
  core2<1, 32>((const char*)P + (size_t)z * 8388608 + (size_t)tileM * 4096,
               (const char*)Vt + (size_t)z * 4194304 + (size_t)tileN * 4096, 4096, 4096,
               smem, acc);
  const int wave = tid >> 6, lane = tid & 63;
  const int wr = wave >> 2, wc = wave & 3, fr = lane & 15, fg = lane >> 4;
  float* O = out + (size_t)z * 2097152;
#pragma unroll
  for (int mi = 0; mi < 4; ++mi) {
#pragma unroll
    for (int jj = 0; jj < 4; ++jj) {
      const int r = wr * 64 + mi * 16 + fg * 4 + jj;
      const float inv = rinv[r];
#pragma unroll
      for (int n = 0; n < 4; ++n)
        O[(size_t)(tileM + r) * 1024 + tileN + wc * 64 + n * 16 + fr] =
            acc[mi * 4 + n][jj] * inv;
    }
  }
}

extern "C" void kernel_launch(void* const* d_in, const int* in_sizes, int n_in,
                              void* d_out, int out_size, void* d_ws, size_t ws_size,
                              hipStream_t stream) {
  if (ws_size < ((size_t)72 << 20)) return;
  const float* x = (const float*)d_in[0];
  const float* Wq = (const float*)d_in[1];
  const float* bq = (const float*)d_in[2];
  const float* Wk = (const float*)d_in[3];
  const float* bk = (const float*)d_in[4];
  const float* Wv = (const float*)d_in[5];
  const float* bv = (const float*)d_in[6];
  char* ws = (char*)d_ws;
  u16* xb = (u16*)(ws);                       // [0,16M); later P~ [4][2048][2048]
  u16* Pb = (u16*)(ws);
  u16* Qb = (u16*)(ws + ((size_t)16 << 20));
  u16* Kb = (u16*)(ws + ((size_t)32 << 20));
  u16* Vt = (u16*)(ws + ((size_t)48 << 20));
  u16* Wb = (u16*)(ws + ((size_t)64 << 20));
  float* rowpart = (float*)(ws + ((size_t)70 << 20));  // 256 KiB
  float* out = (float*)d_out;

  (void)hipFuncSetAttribute((const void*)qkproj_kernel,
                            hipFuncAttributeMaxDynamicSharedMemorySize, 131072);
  (void)hipFuncSetAttribute((const void*)vproj_kernel,
                            hipFuncAttributeMaxDynamicSharedMemorySize, 98304);
  (void)hipFuncSetAttribute((const void*)sc8_kernel,
                            hipFuncAttributeMaxDynamicSharedMemorySize, 131072);
  (void)hipFuncSetAttribute((const void*)pv8_kernel,
                            hipFuncAttributeMaxDynamicSharedMemorySize, 98816);

  cast_all_kernel<<<11264, 256, 0, stream>>>(x, Wq, Wk, Wv, xb, Wb);

  qkproj_kernel<<<dim3(32, 8), 512, 131072, stream>>>(xb, Wb, bq, bk, Qb);
  vproj_kernel<<<dim3(64, 4), 512, 98304, stream>>>(xb, Wb + 2097152, bv, Vt);

  sc8_kernel<<<dim3(8, 8, 4), 512, 131072, stream>>>(Qb, Kb, Pb, rowpart);
  pv8_kernel<<<dim3(16, 4, 4), 512, 98816, stream>>>(Pb, Vt, rowpart, out);
}